// Round 18
// baseline (380.654 us; speedup 1.0000x reference)
//
#include <hip/hip_runtime.h>
#include <hip/hip_bf16.h>

typedef __bf16 bf16_t;
typedef __bf16 bf16x4 __attribute__((ext_vector_type(4)));
typedef __bf16 bf16x8 __attribute__((ext_vector_type(8)));
typedef float f32x4 __attribute__((ext_vector_type(4)));
typedef unsigned int uint;

#define T_TOK 4096
#define H_DIM 7168
#define QLORA 1536
#define KVLORA 512
#define ROPE_D 64
#define NOPE_D 128
#define NHEAD 16
#define NQKV 2112   /* QLORA + KVLORA + ROPE */
#define NQB  3072   /* NHEAD * 192 */
#define EPS_F 1e-6f

// ---- fused preamble: hs cast + 3 weight transposes + cache copies ----------
// Region-dispatch by blockIdx.x:
//   [0, 3696)     : transpose w_qkv_a (7168x2112) -> wqkvaT [2112][7168]
//   [3696, 4848)  : transpose w_q_b   (1536x3072) -> wqbT   [3072][1536]
//   [4848, 5104)  : transpose w_kc    (2048x512)  -> wkcT   [512][2048]
//   [5104, 6128)  : grid-stride cast hs f32 -> bf16 (1024 blocks)
//   [6128, 7152)  : float4 copy k_cache -> kc_out, rope_cache -> rc_out

__device__ inline void transpose_tile64(const float* __restrict__ in,
                                        bf16_t* __restrict__ out,
                                        int R, int C, int bx, int by,
                                        float (*tile)[65])
{
    const int tx = threadIdx.x & 15, ty = threadIdx.x >> 4;
    #pragma unroll
    for (int i = 0; i < 4; i++) {
        const int r = ty + 16 * i;
        const float4 v = *(const float4*)&in[(long)(by + r) * C + bx + tx * 4];
        tile[r][tx * 4 + 0] = v.x; tile[r][tx * 4 + 1] = v.y;
        tile[r][tx * 4 + 2] = v.z; tile[r][tx * 4 + 3] = v.w;
    }
    __syncthreads();
    #pragma unroll
    for (int i = 0; i < 4; i++) {
        const int cc = ty + 16 * i;
        bf16x4 o;
        o[0] = (bf16_t)tile[tx * 4 + 0][cc];
        o[1] = (bf16_t)tile[tx * 4 + 1][cc];
        o[2] = (bf16_t)tile[tx * 4 + 2][cc];
        o[3] = (bf16_t)tile[tx * 4 + 3][cc];
        *(bf16x4*)&out[(long)(bx + cc) * R + by + tx * 4] = o;
    }
}

__global__ __launch_bounds__(256) void preamble_kernel(
    const float* __restrict__ hs, const float* __restrict__ w_qkv_a,
    const float* __restrict__ w_q_b, const float* __restrict__ w_kc,
    const float* __restrict__ k_cache_in, const float* __restrict__ rope_cache_in,
    bf16_t* __restrict__ hs_bf, bf16_t* __restrict__ wqkvaT,
    bf16_t* __restrict__ wqbT, bf16_t* __restrict__ wkcT,
    float* __restrict__ kc_out, float* __restrict__ rc_out)
{
    __shared__ float tile[64][65];
    const int b = blockIdx.x;
    if (b < 3696) {
        transpose_tile64(w_qkv_a, wqkvaT, H_DIM, NQKV, (b % 33) * 64, (b / 33) * 64, tile);
    } else if (b < 4848) {
        const int i = b - 3696;
        transpose_tile64(w_q_b, wqbT, QLORA, NQB, (i % 48) * 64, (i / 48) * 64, tile);
    } else if (b < 5104) {
        const int i = b - 4848;
        transpose_tile64(w_kc, wkcT, 2048, 512, (i % 8) * 64, (i / 8) * 64, tile);
    } else if (b < 6128) {
        const int i = b - 5104;            // 0..1023
        const long n8 = (long)T_TOK * H_DIM / 8;
        const long stride = 1024L * 256;
        for (long idx = (long)i * 256 + threadIdx.x; idx < n8; idx += stride) {
            const float4 a = ((const float4*)hs)[idx * 2];
            const float4 c = ((const float4*)hs)[idx * 2 + 1];
            bf16x8 v;
            v[0] = (bf16_t)a.x; v[1] = (bf16_t)a.y; v[2] = (bf16_t)a.z; v[3] = (bf16_t)a.w;
            v[4] = (bf16_t)c.x; v[5] = (bf16_t)c.y; v[6] = (bf16_t)c.z; v[7] = (bf16_t)c.w;
            ((bf16x8*)hs_bf)[idx] = v;
        }
    } else {
        const int i = b - 6128;            // 0..1023
        const long nkc = 2097152;          // 16384*512/4 float4
        const long ntot = 2359296;         // + 16384*64/4
        const long stride = 1024L * 256;
        for (long idx = (long)i * 256 + threadIdx.x; idx < ntot; idx += stride) {
            if (idx < nkc) ((float4*)kc_out)[idx] = ((const float4*)k_cache_in)[idx];
            else ((float4*)rc_out)[idx - nkc] = ((const float4*)rope_cache_in)[idx - nkc];
        }
    }
}

// block reduction safe for repeated use (leading+trailing barriers)
__device__ inline float block_sum_256(float v)
{
    #pragma unroll
    for (int off = 32; off > 0; off >>= 1) v += __shfl_xor(v, off, 64);
    __shared__ float tmp[4];
    __syncthreads();
    if ((threadIdx.x & 63) == 0) tmp[threadIdx.x >> 6] = v;
    __syncthreads();
    return tmp[0] + tmp[1] + tmp[2] + tmp[3];
}

// fused: RMS-norm q-lora -> bf16 q_a;  RMS-norm latent + rope -> k_out/caches.
// qkv partials are bf16 (GEMM1 output); vectorized bf16x8 loads (G13).
__global__ __launch_bounds__(256) void rmsq_kside_kernel(
    const bf16_t* __restrict__ qkv, const bf16_t* __restrict__ qB,
    const float* __restrict__ q_w, const float* __restrict__ kv_w,
    const float* __restrict__ cos_sin, const int* __restrict__ positions,
    const int* __restrict__ slot_map,
    bf16_t* __restrict__ q_a, float* __restrict__ k_out,
    float* __restrict__ kc_out, float* __restrict__ rc_out)
{
    const int t = blockIdx.x;
    const int tx = threadIdx.x;
    const long base = (long)t * NQKV;

    // ---- q side: 1536 = 192 chunks x 8 (threads 0..191) ----
    float v[8];
    float ss = 0.f;
    if (tx < 192) {
        const bf16x8 a = *(const bf16x8*)(qkv + base + tx * 8);
        if (qB) {
            const bf16x8 b = *(const bf16x8*)(qB + base + tx * 8);
            #pragma unroll
            for (int j = 0; j < 8; j++) v[j] = (float)a[j] + (float)b[j];
        } else {
            #pragma unroll
            for (int j = 0; j < 8; j++) v[j] = (float)a[j];
        }
        #pragma unroll
        for (int j = 0; j < 8; j++) ss += v[j] * v[j];
    }
    ss = block_sum_256(ss);
    const float scq = rsqrtf(ss / (float)QLORA + EPS_F);
    if (tx < 192) {
        const float4 w0 = ((const float4*)q_w)[tx * 2];
        const float4 w1 = ((const float4*)q_w)[tx * 2 + 1];
        bf16x8 o;
        o[0] = (bf16_t)(v[0] * scq * w0.x); o[1] = (bf16_t)(v[1] * scq * w0.y);
        o[2] = (bf16_t)(v[2] * scq * w0.z); o[3] = (bf16_t)(v[3] * scq * w0.w);
        o[4] = (bf16_t)(v[4] * scq * w1.x); o[5] = (bf16_t)(v[5] * scq * w1.y);
        o[6] = (bf16_t)(v[6] * scq * w1.z); o[7] = (bf16_t)(v[7] * scq * w1.w);
        *(bf16x8*)(q_a + (long)t * QLORA + tx * 8) = o;
    }

    // ---- k side: latent 512 = 64 chunks x 8 (threads 0..63) ----
    float kv[8];
    float ssk = 0.f;
    if (tx < 64) {
        const bf16x8 a = *(const bf16x8*)(qkv + base + QLORA + tx * 8);
        if (qB) {
            const bf16x8 b = *(const bf16x8*)(qB + base + QLORA + tx * 8);
            #pragma unroll
            for (int j = 0; j < 8; j++) kv[j] = (float)a[j] + (float)b[j];
        } else {
            #pragma unroll
            for (int j = 0; j < 8; j++) kv[j] = (float)a[j];
        }
        #pragma unroll
        for (int j = 0; j < 8; j++) ssk += kv[j] * kv[j];
    }
    ssk = block_sum_256(ssk);
    const float sck = rsqrtf(ssk / (float)KVLORA + EPS_F);
    const int slot = slot_map[t];
    if (tx < 64) {
        const float4 w0 = ((const float4*)kv_w)[tx * 2];
        const float4 w1 = ((const float4*)kv_w)[tx * 2 + 1];
        float4 o0, o1;
        o0.x = kv[0] * sck * w0.x; o0.y = kv[1] * sck * w0.y;
        o0.z = kv[2] * sck * w0.z; o0.w = kv[3] * sck * w0.w;
        o1.x = kv[4] * sck * w1.x; o1.y = kv[5] * sck * w1.y;
        o1.z = kv[6] * sck * w1.z; o1.w = kv[7] * sck * w1.w;
        *(float4*)(k_out + (long)t * 576 + tx * 8)     = o0;
        *(float4*)(k_out + (long)t * 576 + tx * 8 + 4) = o1;
        *(float4*)(kc_out + (long)slot * KVLORA + tx * 8)     = o0;
        *(float4*)(kc_out + (long)slot * KVLORA + tx * 8 + 4) = o1;
    }
    if (tx < 32) {
        const int j = tx;
        const int pos = positions[t];
        const float c = cos_sin[pos * 64 + j];
        const float s = cos_sin[pos * 64 + 32 + j];
        float x1 = (float)qkv[base + QLORA + KVLORA + 2 * j];
        float x2 = (float)qkv[base + QLORA + KVLORA + 2 * j + 1];
        if (qB) {
            x1 += (float)qB[base + QLORA + KVLORA + 2 * j];
            x2 += (float)qB[base + QLORA + KVLORA + 2 * j + 1];
        }
        const float o1 = x1 * c - x2 * s;
        const float o2 = x2 * c + x1 * s;
        k_out[(long)t * 576 + 512 + j]      = o1;
        k_out[(long)t * 576 + 512 + 32 + j] = o2;
        rc_out[(long)slot * 64 + j]      = o1;
        rc_out[(long)slot * 64 + 32 + j] = o2;
    }
}

// ---- r8 skeleton + K-split wave pairs: 128x128, BK=64, 8 waves -------------
// Column-major block decode (bx = swz/gy): consecutive blocks share one
// B-panel (918 KB, L2-resident) and walk M -> better B reuse.
// Wave w: quadrant q=w>>1 (qr,qc), parity p=w&1 handles ks-half p only.
// Pairwise acc reduction through dead staging LDS; C output bf16.
// T5: setprio(1) around the MFMA cluster (verified +10%, r14).
#define GBM 128
#define GBN 128
#define GBK 64

#define KSPLIT_TILE_COMPUTE(aa, bb)                                                          \
    bf16x8 a0, a1, a2, a3, b0, b1, b2, b3;                                                   \
    asm volatile("ds_read_b128 %0, %1 offset:0"    : "=v"(a0) : "v"(aa));                    \
    asm volatile("ds_read_b128 %0, %1 offset:2048" : "=v"(a1) : "v"(aa));                    \
    asm volatile("ds_read_b128 %0, %1 offset:4096" : "=v"(a2) : "v"(aa));                    \
    asm volatile("ds_read_b128 %0, %1 offset:6144" : "=v"(a3) : "v"(aa));                    \
    asm volatile("ds_read_b128 %0, %1 offset:0"    : "=v"(b0) : "v"(bb));                    \
    asm volatile("ds_read_b128 %0, %1 offset:2048" : "=v"(b1) : "v"(bb));                    \
    asm volatile("ds_read_b128 %0, %1 offset:4096" : "=v"(b2) : "v"(bb));                    \
    asm volatile("ds_read_b128 %0, %1 offset:6144" : "=v"(b3) : "v"(bb));                    \
    asm volatile("s_waitcnt lgkmcnt(0)" ::: "memory");                                       \
    __builtin_amdgcn_sched_barrier(0);                                                       \
    __builtin_amdgcn_s_setprio(1);                                                           \
    acc[0][0] = __builtin_amdgcn_mfma_f32_16x16x32_bf16(a0, b0, acc[0][0], 0, 0, 0);         \
    acc[0][1] = __builtin_amdgcn_mfma_f32_16x16x32_bf16(a0, b1, acc[0][1], 0, 0, 0);         \
    acc[0][2] = __builtin_amdgcn_mfma_f32_16x16x32_bf16(a0, b2, acc[0][2], 0, 0, 0);         \
    acc[0][3] = __builtin_amdgcn_mfma_f32_16x16x32_bf16(a0, b3, acc[0][3], 0, 0, 0);         \
    acc[1][0] = __builtin_amdgcn_mfma_f32_16x16x32_bf16(a1, b0, acc[1][0], 0, 0, 0);         \
    acc[1][1] = __builtin_amdgcn_mfma_f32_16x16x32_bf16(a1, b1, acc[1][1], 0, 0, 0);         \
    acc[1][2] = __builtin_amdgcn_mfma_f32_16x16x32_bf16(a1, b2, acc[1][2], 0, 0, 0);         \
    acc[1][3] = __builtin_amdgcn_mfma_f32_16x16x32_bf16(a1, b3, acc[1][3], 0, 0, 0);         \
    acc[2][0] = __builtin_amdgcn_mfma_f32_16x16x32_bf16(a2, b0, acc[2][0], 0, 0, 0);         \
    acc[2][1] = __builtin_amdgcn_mfma_f32_16x16x32_bf16(a2, b1, acc[2][1], 0, 0, 0);         \
    acc[2][2] = __builtin_amdgcn_mfma_f32_16x16x32_bf16(a2, b2, acc[2][2], 0, 0, 0);         \
    acc[2][3] = __builtin_amdgcn_mfma_f32_16x16x32_bf16(a2, b3, acc[2][3], 0, 0, 0);         \
    acc[3][0] = __builtin_amdgcn_mfma_f32_16x16x32_bf16(a3, b0, acc[3][0], 0, 0, 0);         \
    acc[3][1] = __builtin_amdgcn_mfma_f32_16x16x32_bf16(a3, b1, acc[3][1], 0, 0, 0);         \
    acc[3][2] = __builtin_amdgcn_mfma_f32_16x16x32_bf16(a3, b2, acc[3][2], 0, 0, 0);         \
    acc[3][3] = __builtin_amdgcn_mfma_f32_16x16x32_bf16(a3, b3, acc[3][3], 0, 0, 0);         \
    __builtin_amdgcn_s_setprio(0);

__global__ __launch_bounds__(512, 4) void gemm_mfma(
    const bf16_t* __restrict__ A, int lda, long sA,
    const bf16_t* __restrict__ Bt, int ldb, long sB,
    bf16_t* __restrict__ C, int ldc, long sC,
    int K, int N)
{
    __shared__ bf16_t As[2][GBM * GBK];   // 2 x 16 KB
    __shared__ bf16_t Bs[2][GBN * GBK];   // 2 x 16 KB

    const int nwg = gridDim.x * gridDim.y;
    const int bid = blockIdx.y * gridDim.x + blockIdx.x;
    const int cpx = nwg >> 3;
    const int swz = (bid & 7) * cpx + (bid >> 3);
    const int bx = swz / gridDim.y;       // column-major decode: B-panel-major
    const int by = swz % gridDim.y;

    const int tid = threadIdx.x;
    const int lane = tid & 63;
    const int w = tid >> 6;            // 0..7
    const int q = w >> 1;              // quadrant 0..3
    const int p = w & 1;               // ks-half parity
    const int qr = q >> 1, qc = q & 1;
    const int fr = lane & 15;
    const int kg = lane >> 4;

    const long brow = (long)by * GBM;
    const long bcol = (long)bx * GBN;

    const bf16_t* Ab = A + blockIdx.z * sA + brow * lda;
    const bf16_t* Bb = Bt + blockIdx.z * sB;
    bf16_t* Cb = C + blockIdx.z * sC + brow * ldc;

    const int srow = w * 16 + (lane >> 3);
    const int scol = (((lane & 7) ^ (lane >> 3)) * 8);

    const uint rd_sw = (uint)(((kg * 16) ^ ((fr & 7) << 4)) ^ (p << 6));
    const uint a_base = (uint)(uintptr_t)(&As[0][0]) + (uint)((qr * 64 + fr) * 128) + rd_sw;
    const uint b_base = (uint)(uintptr_t)(&Bs[0][0]) + (uint)((qc * 64 + fr) * 128) + rd_sw;

    f32x4 acc[4][4] = {};

    const int nt = K / GBK;

    auto stage = [&](int buf, int k0) {
        #pragma unroll
        for (int it = 0; it < 2; it++) {
            const int r = srow + it * 8;
            __builtin_amdgcn_global_load_lds(
                (const __attribute__((address_space(1))) void*)(Ab + (long)r * lda + k0 + scol),
                (__attribute__((address_space(3))) void*)(&As[buf][(w * 16 + it * 8) * GBK]),
                16, 0, 0);
        }
        #pragma unroll
        for (int it = 0; it < 2; it++) {
            const int r = srow + it * 8;
            long bn = bcol + r; if (bn >= N) bn = N - 1;
            __builtin_amdgcn_global_load_lds(
                (const __attribute__((address_space(1))) void*)(Bb + bn * ldb + k0 + scol),
                (__attribute__((address_space(3))) void*)(&Bs[buf][(w * 16 + it * 8) * GBK]),
                16, 0, 0);
        }
    };

    stage(0, 0);
    asm volatile("s_waitcnt vmcnt(0)" ::: "memory");
    __builtin_amdgcn_s_barrier();

    int cur = 0;
    for (int t = 0; t < nt; ++t) {
        if (t + 1 < nt) stage(cur ^ 1, (t + 1) * GBK);

        const uint aa = a_base + (uint)(cur * (GBM * GBK * 2));
        const uint bb = b_base + (uint)(cur * (GBN * GBK * 2));
        { KSPLIT_TILE_COMPUTE(aa, bb) }

        asm volatile("s_waitcnt vmcnt(0)" ::: "memory");
        __builtin_amdgcn_s_barrier();
        cur ^= 1;
    }

    float* red = (q < 2) ? (float*)&As[0][0] : (float*)&Bs[0][0];
    red += (q & 1) * 4096;   // 16 KB per quadrant
    if (p == 1) {
        #pragma unroll
        for (int i = 0; i < 4; i++)
            #pragma unroll
            for (int j = 0; j < 4; j++)
                *(f32x4*)&red[(i * 4 + j) * 256 + lane * 4] = acc[i][j];
    }
    __syncthreads();
    if (p == 0) {
        #pragma unroll
        for (int i = 0; i < 4; i++) {
            #pragma unroll
            for (int j = 0; j < 4; j++) {
                acc[i][j] += *(const f32x4*)&red[(i * 4 + j) * 256 + lane * 4];
                const int row0 = qr * 64 + i * 16 + kg * 4;
                const long col = bcol + qc * 64 + j * 16 + fr;
                if (col < N) {
                    #pragma unroll
                    for (int r = 0; r < 4; r++)
                        Cb[(long)(row0 + r) * ldc + col] = (bf16_t)acc[i][j][r];
                }
            }
        }
    }
}

// ---------------- GEMM2 (K-split pairs) with fused split_q epilogue ----------
__global__ __launch_bounds__(512, 4) void gemm2_fused(
    const bf16_t* __restrict__ A,   // q_a, lda=QLORA
    const bf16_t* __restrict__ Bt,  // wqbT, ldb=QLORA
    const float* __restrict__ cos_sin,
    const int* __restrict__ positions,
    bf16_t* __restrict__ q_nope,
    float* __restrict__ q_out)
{
    __shared__ bf16_t As[2][GBM * GBK];
    __shared__ bf16_t Bs[2][GBN * GBK];

    const int nwg = gridDim.x * gridDim.y;
    const int bid = blockIdx.y * gridDim.x + blockIdx.x;
    const int cpx = nwg >> 3;
    const int swz = (bid & 7) * cpx + (bid >> 3);
    const int bx = swz / gridDim.y;       // column-major decode
    const int by = swz % gridDim.y;

    const int tid = threadIdx.x;
    const int lane = tid & 63;
    const int w = tid >> 6;
    const int q = w >> 1;
    const int p = w & 1;
    const int qr = q >> 1, qc = q & 1;
    const int fr = lane & 15;
    const int kg = lane >> 4;

    const int brow = by * GBM;
    const int bcol = bx * GBN;

    const bf16_t* Ab = A + (long)brow * QLORA;
    const bf16_t* Bb = Bt + (long)bcol * QLORA;

    const int srow = w * 16 + (lane >> 3);
    const int scol = (((lane & 7) ^ (lane >> 3)) * 8);

    const uint rd_sw = (uint)(((kg * 16) ^ ((fr & 7) << 4)) ^ (p << 6));
    const uint a_base = (uint)(uintptr_t)(&As[0][0]) + (uint)((qr * 64 + fr) * 128) + rd_sw;
    const uint b_base = (uint)(uintptr_t)(&Bs[0][0]) + (uint)((qc * 64 + fr) * 128) + rd_sw;

    f32x4 acc[4][4] = {};

    const int nt = QLORA / GBK;   // 24

    auto stage = [&](int buf, int k0) {
        #pragma unroll
        for (int it = 0; it < 2; it++) {
            const int r = srow + it * 8;
            __builtin_amdgcn_global_load_lds(
                (const __attribute__((address_space(1))) void*)(Ab + (long)r * QLORA + k0 + scol),
                (__attribute__((address_space(3))) void*)(&As[buf][(w * 16 + it * 8) * GBK]),
                16, 0, 0);
            __builtin_amdgcn_global_load_lds(
                (const __attribute__((address_space(1))) void*)(Bb + (long)r * QLORA + k0 + scol),
                (__attribute__((address_space(3))) void*)(&Bs[buf][(w * 16 + it * 8) * GBK]),
                16, 0, 0);
        }
    };

    stage(0, 0);
    asm volatile("s_waitcnt vmcnt(0)" ::: "memory");
    __builtin_amdgcn_s_barrier();

    int cur = 0;
    for (int t = 0; t < nt; ++t) {
        if (t + 1 < nt) stage(cur ^ 1, (t + 1) * GBK);

        const uint aa = a_base + (uint)(cur * (GBM * GBK * 2));
        const uint bb = b_base + (uint)(cur * (GBN * GBK * 2));
        { KSPLIT_TILE_COMPUTE(aa, bb) }

        asm volatile("s_waitcnt vmcnt(0)" ::: "memory");
        __builtin_amdgcn_s_barrier();
        cur ^= 1;
    }

    float* red = (q < 2) ? (float*)&As[0][0] : (float*)&Bs[0][0];
    red += (q & 1) * 4096;
    if (p == 1) {
        #pragma unroll
        for (int i = 0; i < 4; i++)
            #pragma unroll
            for (int j = 0; j < 4; j++)
                *(f32x4*)&red[(i * 4 + j) * 256 + lane * 4] = acc[i][j];
    }
    __syncthreads();
    if (p == 0) {
        #pragma unroll
        for (int i = 0; i < 4; i++) {
            #pragma unroll
            for (int j = 0; j < 4; j++) {
                acc[i][j] += *(const f32x4*)&red[(i * 4 + j) * 256 + lane * 4];
                const int row0 = qr * 64 + i * 16 + kg * 4;
                const int col  = bcol + qc * 64 + j * 16 + fr;
                const int h  = col / 192;
                const int jj = col - h * 192;
                if (jj < 128) {
                    #pragma unroll
                    for (int r = 0; r < 4; r++) {
                        const int t = brow + row0 + r;
                        q_nope[((long)h * T_TOK + t) * NOPE_D + jj] = (bf16_t)acc[i][j][r];
                    }
                } else {
                    const int idx = jj - 128;
                    const int j2 = idx >> 1;
                    const int odd = idx & 1;
                    #pragma unroll
                    for (int r = 0; r < 4; r++) {
                        const int t = brow + row0 + r;
                        const float v = acc[i][j][r];
                        const float pr = __shfl_xor(v, 1, 64);
                        const int pos = positions[t];
                        const float c = cos_sin[pos * 64 + j2];
                        const float s = cos_sin[pos * 64 + 32 + j2];
                        const float o = odd ? (v * c + pr * s) : (v * c - pr * s);
                        q_out[(long)t * 9216 + h * 576 + 512 + (odd ? 32 : 0) + j2] = o;
                    }
                }
            }
        }
    }
}

// ---------------- GEMM3: single-shot K=128 kernel ---------------------------
__global__ __launch_bounds__(512) void gemm3_k128(
    const bf16_t* __restrict__ A,   // q_nope, lda=128, head stride T*128
    const bf16_t* __restrict__ Bt,  // wkcT, ldb=2048, head stride 128
    float* __restrict__ C)          // q_out, ldc=9216, head stride 576
{
    __shared__ bf16_t As[2][GBM * GBK];
    __shared__ bf16_t Bs[2][GBN * GBK];

    const int nwg = gridDim.x * gridDim.y;
    const int bid = blockIdx.y * gridDim.x + blockIdx.x;
    const int cpx = nwg >> 3;
    const int swz = (bid & 7) * cpx + (bid >> 3);
    const int bx = swz / gridDim.y;       // column-major decode
    const int by = swz % gridDim.y;

    const int tid = threadIdx.x;
    const int lane = tid & 63;
    const int w = tid >> 6;
    const int wr = w >> 2, wc = w & 3;   // wave tile 64x32
    const int fr = lane & 15;
    const int kg = lane >> 4;

    const long brow = (long)by * GBM;
    const long bcol = (long)bx * GBN;

    const bf16_t* Ab = A + (long)blockIdx.z * T_TOK * NOPE_D + brow * NOPE_D;
    const bf16_t* Bb = Bt + blockIdx.z * 128;
    float* Cb = C + blockIdx.z * 576 + brow * 9216;

    const int srow = w * 16 + (lane >> 3);
    const int scol = (((lane & 7) ^ (lane >> 3)) * 8);

    const uint rd_sw = (uint)((kg * 16) ^ ((fr & 7) << 4));

    #pragma unroll
    for (int kh = 0; kh < 2; kh++) {
        #pragma unroll
        for (int it = 0; it < 2; it++) {
            const int r = srow + it * 8;
            __builtin_amdgcn_global_load_lds(
                (const __attribute__((address_space(1))) void*)(Ab + (long)r * NOPE_D + kh * 64 + scol),
                (__attribute__((address_space(3))) void*)(&As[kh][(w * 16 + it * 8) * GBK]),
                16, 0, 0);
        }
        #pragma unroll
        for (int it = 0; it < 2; it++) {
            const int r = srow + it * 8;
            __builtin_amdgcn_global_load_lds(
                (const __attribute__((address_space(1))) void*)(Bb + (bcol + r) * 2048 + kh * 64 + scol),
                (__attribute__((address_space(3))) void*)(&Bs[kh][(w * 16 + it * 8) * GBK]),
                16, 0, 0);
        }
    }
    asm volatile("s_waitcnt vmcnt(0)" ::: "memory");
    __builtin_amdgcn_s_barrier();

    f32x4 acc[4][2] = {};

    #pragma unroll
    for (int kh = 0; kh < 2; kh++) {
        const uint aa  = (uint)(uintptr_t)(&As[kh][0]) + (uint)((wr * 64 + fr) * 128) + rd_sw;
        const uint bb  = (uint)(uintptr_t)(&Bs[kh][0]) + (uint)((wc * 32 + fr) * 128) + rd_sw;
        const uint aaX = aa ^ 64u;
        const uint bbX = bb ^ 64u;
        bf16x8 a00, a01, a02, a03, a10, a11, a12, a13, b00, b01, b10, b11;
        asm volatile("ds_read_b128 %0, %1 offset:0"    : "=v"(a00) : "v"(aa));
        asm volatile("ds_read_b128 %0, %1 offset:2048" : "=v"(a01) : "v"(aa));
        asm volatile("ds_read_b128 %0, %1 offset:4096" : "=v"(a02) : "v"(aa));
        asm volatile("ds_read_b128 %0, %1 offset:6144" : "=v"(a03) : "v"(aa));
        asm volatile("ds_read_b128 %0, %1 offset:0"    : "=v"(a10) : "v"(aaX));
        asm volatile("ds_read_b128 %0, %1 offset:2048" : "=v"(a11) : "v"(aaX));
        asm volatile("ds_read_b128 %0, %1 offset:4096" : "=v"(a12) : "v"(aaX));
        asm volatile("ds_read_b128 %0, %1 offset:6144" : "=v"(a13) : "v"(aaX));
        asm volatile("ds_read_b128 %0, %1 offset:0"    : "=v"(b00) : "v"(bb));
        asm volatile("ds_read_b128 %0, %1 offset:2048" : "=v"(b01) : "v"(bb));
        asm volatile("ds_read_b128 %0, %1 offset:0"    : "=v"(b10) : "v"(bbX));
        asm volatile("ds_read_b128 %0, %1 offset:2048" : "=v"(b11) : "v"(bbX));
        asm volatile("s_waitcnt lgkmcnt(0)" ::: "memory");
        __builtin_amdgcn_sched_barrier(0);

        __builtin_amdgcn_s_setprio(1);
        acc[0][0] = __builtin_amdgcn_mfma_f32_16x16x32_bf16(a00, b00, acc[0][0], 0, 0, 0);
        acc[0][1] = __builtin_amdgcn_mfma_f32_16x16x32_bf16(a00, b01, acc[0][1], 0, 0, 0);
        acc[1][0] = __builtin_amdgcn_mfma_f32_16x16x32_bf16(a01, b00, acc[1][0], 0, 0, 0);
        acc[1][1] = __builtin_amdgcn_mfma_f32_16x16x32_bf16(a01, b01, acc[1][1], 0, 0, 0);
        acc[2][0] = __builtin_amdgcn_mfma_f32_16x16x32_bf16(a02, b00, acc[2][0], 0, 0, 0);
        acc[2][1] = __builtin_amdgcn_mfma_f32_16x16x32_bf16(a02, b01, acc[2][1], 0, 0, 0);
        acc[3][0] = __builtin_amdgcn_mfma_f32_16x16x32_bf16(a03, b00, acc[3][0], 0, 0, 0);
        acc[3][1] = __builtin_amdgcn_mfma_f32_16x16x32_bf16(a03, b01, acc[3][1], 0, 0, 0);
        acc[0][0] = __builtin_amdgcn_mfma_f32_16x16x32_bf16(a10, b10, acc[0][0], 0, 0, 0);
        acc[0][1] = __builtin_amdgcn_mfma_f32_16x16x32_bf16(a10, b11, acc[0][1], 0, 0, 0);
        acc[1][0] = __builtin_amdgcn_mfma_f32_16x16x32_bf16(a11, b10, acc[1][0], 0, 0, 0);
        acc[1][1] = __builtin_amdgcn_mfma_f32_16x16x32_bf16(a11, b11, acc[1][1], 0, 0, 0);
        acc[2][0] = __builtin_amdgcn_mfma_f32_16x16x32_bf16(a12, b10, acc[2][0], 0, 0, 0);
        acc[2][1] = __builtin_amdgcn_mfma_f32_16x16x32_bf16(a12, b11, acc[2][1], 0, 0, 0);
        acc[3][0] = __builtin_amdgcn_mfma_f32_16x16x32_bf16(a13, b10, acc[3][0], 0, 0, 0);
        acc[3][1] = __builtin_amdgcn_mfma_f32_16x16x32_bf16(a13, b11, acc[3][1], 0, 0, 0);
        __builtin_amdgcn_s_setprio(0);
    }

    #pragma unroll
    for (int i = 0; i < 4; i++) {
        #pragma unroll
        for (int j = 0; j < 2; j++) {
            const int row0 = wr * 64 + i * 16 + kg * 4;
            const long col = bcol + wc * 32 + j * 16 + fr;
            #pragma unroll
            for (int r = 0; r < 4; r++)
                Cb[(long)(row0 + r) * 9216 + col] = acc[i][j][r];
        }
    }
}

// ---------------- launcher ----------------

extern "C" void kernel_launch(void* const* d_in, const int* in_sizes, int n_in,
                              void* d_out, int out_size, void* d_ws, size_t ws_size,
                              hipStream_t stream)
{
    const float* hs       = (const float*)d_in[0];
    const int*   positions= (const int*)d_in[1];
    const float* w_qkv_a  = (const float*)d_in[2];
    const float* q_a_ln_w = (const float*)d_in[3];
    const float* w_q_b    = (const float*)d_in[4];
    const float* kv_a_ln_w= (const float*)d_in[5];
    const float* w_kc     = (const float*)d_in[6];
    const float* cos_sin  = (const float*)d_in[7];
    const float* k_cache_in  = (const float*)d_in[8];
    const float* rope_cache_in = (const float*)d_in[9];
    const int*   slot_map = (const int*)d_in[10];

    float* out   = (float*)d_out;
    float* q_out = out;                       // 4096*16*576
    float* k_out = out + 37748736;            // 4096*576
    float* kc_out = out + 40108032;           // 16384*512
    float* rc_out = out + 48496640;           // 16384*64

    char* ws = (char*)d_ws;
    bf16_t* hs_bf  = (bf16_t*)(ws + 0);            // 58,720,256 B
    bf16_t* wqkvaT = (bf16_t*)(ws + 58720256);     // 30,277,632 B
    bf16_t* wqbT   = (bf16_t*)(ws + 88997888);     //  9,437,184 B
    bf16_t* wkcT   = (bf16_t*)(ws + 98435072);     //  2,097,152 B
    bf16_t* qkv0   = (bf16_t*)(ws + 100532224);    // 17,301,504 B (bf16 partial)

    const bool splitk = ws_size >= (size_t)169738240;

    bf16_t* qkv1 = nullptr;
    bf16_t* q_a;
    bf16_t* q_nope;
    if (splitk) {
        qkv1   = (bf16_t*)(ws + 117833728);        // 17,301,504 B -> ends 135,135,232
        q_a    = (bf16_t*)(ws + 0);                // hs_bf region, dead after GEMM1
        q_nope = (bf16_t*)(ws + 117833728);        // reuse qkv1 slot after rmsq_kside
    } else {
        q_a    = (bf16_t*)(ws + 135135232);
        q_nope = (bf16_t*)(ws + 100532224);        // reuse qkv0 slot
    }

    // fused preamble: hs cast + 3 weight transposes + cache copies, one launch
    preamble_kernel<<<7152, 256, 0, stream>>>(hs, w_qkv_a, w_q_b, w_kc,
                                              k_cache_in, rope_cache_in,
                                              hs_bf, wqkvaT, wqbT, wkcT,
                                              kc_out, rc_out);

    // GEMM1: qkv = hs @ w_qkv_a   (4096 x 2112, K=7168), split-K=2, bf16 partials
    if (splitk) {
        gemm_mfma<<<dim3((NQKV + GBN - 1) / GBN, T_TOK / GBM, 2), 512, 0, stream>>>(
            hs_bf, H_DIM, 3584, wqkvaT, H_DIM, 3584,
            qkv0, NQKV, (long)T_TOK * NQKV, 3584, NQKV);
    } else {
        gemm_mfma<<<dim3((NQKV + GBN - 1) / GBN, T_TOK / GBM, 1), 512, 0, stream>>>(
            hs_bf, H_DIM, 0, wqkvaT, H_DIM, 0, qkv0, NQKV, 0, H_DIM, NQKV);
    }

    rmsq_kside_kernel<<<T_TOK, 256, 0, stream>>>(qkv0, qkv1, q_a_ln_w, kv_a_ln_w,
                                                 cos_sin, positions, slot_map,
                                                 q_a, k_out, kc_out, rc_out);

    // GEMM2 + fused split_q
    gemm2_fused<<<dim3(NQB / GBN, T_TOK / GBM), 512, 0, stream>>>(
        q_a, wqbT, cos_sin, positions, q_nope, q_out);

    // GEMM3 (batched over heads): single-shot K=128
    gemm3_k128<<<dim3(KVLORA / GBN, T_TOK / GBM, NHEAD), 512, 0, stream>>>(
        q_nope, wkcT, q_out);
}

// Round 19
// 337.701 us; speedup vs baseline: 1.1272x; 1.1272x over previous
//
#include <hip/hip_runtime.h>
#include <hip/hip_bf16.h>

typedef __bf16 bf16_t;
typedef __bf16 bf16x4 __attribute__((ext_vector_type(4)));
typedef __bf16 bf16x8 __attribute__((ext_vector_type(8)));
typedef float f32x4 __attribute__((ext_vector_type(4)));
typedef unsigned int uint;

#define T_TOK 4096
#define H_DIM 7168
#define QLORA 1536
#define KVLORA 512
#define ROPE_D 64
#define NOPE_D 128
#define NHEAD 16
#define NQKV 2112   /* QLORA + KVLORA + ROPE */
#define NQB  3072   /* NHEAD * 192 */
#define EPS_F 1e-6f

// ---------------- fused preamble: hs cast + 3 weight transposes -------------
__device__ inline void transpose_tile64(const float* __restrict__ in,
                                        bf16_t* __restrict__ out,
                                        int R, int C, int bx, int by,
                                        float (*tile)[65])
{
    const int tx = threadIdx.x & 15, ty = threadIdx.x >> 4;
    #pragma unroll
    for (int i = 0; i < 4; i++) {
        const int r = ty + 16 * i;
        const float4 v = *(const float4*)&in[(long)(by + r) * C + bx + tx * 4];
        tile[r][tx * 4 + 0] = v.x; tile[r][tx * 4 + 1] = v.y;
        tile[r][tx * 4 + 2] = v.z; tile[r][tx * 4 + 3] = v.w;
    }
    __syncthreads();
    #pragma unroll
    for (int i = 0; i < 4; i++) {
        const int cc = ty + 16 * i;
        bf16x4 o;
        o[0] = (bf16_t)tile[tx * 4 + 0][cc];
        o[1] = (bf16_t)tile[tx * 4 + 1][cc];
        o[2] = (bf16_t)tile[tx * 4 + 2][cc];
        o[3] = (bf16_t)tile[tx * 4 + 3][cc];
        *(bf16x4*)&out[(long)(bx + cc) * R + by + tx * 4] = o;
    }
}

__global__ __launch_bounds__(256) void preamble_kernel(
    const float* __restrict__ hs, const float* __restrict__ w_qkv_a,
    const float* __restrict__ w_q_b, const float* __restrict__ w_kc,
    bf16_t* __restrict__ hs_bf, bf16_t* __restrict__ wqkvaT,
    bf16_t* __restrict__ wqbT, bf16_t* __restrict__ wkcT)
{
    __shared__ float tile[64][65];
    const int b = blockIdx.x;
    if (b < 3696) {
        transpose_tile64(w_qkv_a, wqkvaT, H_DIM, NQKV, (b % 33) * 64, (b / 33) * 64, tile);
    } else if (b < 4848) {
        const int i = b - 3696;
        transpose_tile64(w_q_b, wqbT, QLORA, NQB, (i % 48) * 64, (i / 48) * 64, tile);
    } else if (b < 5104) {
        const int i = b - 4848;
        transpose_tile64(w_kc, wkcT, 2048, 512, (i % 8) * 64, (i / 8) * 64, tile);
    } else {
        const int i = b - 5104;            // 0..1023
        const long n8 = (long)T_TOK * H_DIM / 8;
        const long stride = 1024L * 256;
        for (long idx = (long)i * 256 + threadIdx.x; idx < n8; idx += stride) {
            const float4 a = ((const float4*)hs)[idx * 2];
            const float4 c = ((const float4*)hs)[idx * 2 + 1];
            bf16x8 v;
            v[0] = (bf16_t)a.x; v[1] = (bf16_t)a.y; v[2] = (bf16_t)a.z; v[3] = (bf16_t)a.w;
            v[4] = (bf16_t)c.x; v[5] = (bf16_t)c.y; v[6] = (bf16_t)c.z; v[7] = (bf16_t)c.w;
            ((bf16x8*)hs_bf)[idx] = v;
        }
    }
}

// block reduction safe for repeated use (leading+trailing barriers)
__device__ inline float block_sum_256(float v)
{
    #pragma unroll
    for (int off = 32; off > 0; off >>= 1) v += __shfl_xor(v, off, 64);
    __shared__ float tmp[4];
    __syncthreads();
    if ((threadIdx.x & 63) == 0) tmp[threadIdx.x >> 6] = v;
    __syncthreads();
    return tmp[0] + tmp[1] + tmp[2] + tmp[3];
}

// fused: RMS-norm q-lora -> bf16 q_a;  RMS-norm latent + rope -> k_out/caches.
// qkv partials are bf16 (GEMM1 output); vectorized bf16x8 loads (G13).
__global__ __launch_bounds__(256) void rmsq_kside_kernel(
    const bf16_t* __restrict__ qkv, const bf16_t* __restrict__ qB,
    const float* __restrict__ q_w, const float* __restrict__ kv_w,
    const float* __restrict__ cos_sin, const int* __restrict__ positions,
    const int* __restrict__ slot_map,
    bf16_t* __restrict__ q_a, float* __restrict__ k_out,
    float* __restrict__ kc_out, float* __restrict__ rc_out)
{
    const int t = blockIdx.x;
    const int tx = threadIdx.x;
    const long base = (long)t * NQKV;

    // ---- q side: 1536 = 192 chunks x 8 (threads 0..191) ----
    float v[8];
    float ss = 0.f;
    if (tx < 192) {
        const bf16x8 a = *(const bf16x8*)(qkv + base + tx * 8);
        if (qB) {
            const bf16x8 b = *(const bf16x8*)(qB + base + tx * 8);
            #pragma unroll
            for (int j = 0; j < 8; j++) v[j] = (float)a[j] + (float)b[j];
        } else {
            #pragma unroll
            for (int j = 0; j < 8; j++) v[j] = (float)a[j];
        }
        #pragma unroll
        for (int j = 0; j < 8; j++) ss += v[j] * v[j];
    }
    ss = block_sum_256(ss);
    const float scq = rsqrtf(ss / (float)QLORA + EPS_F);
    if (tx < 192) {
        const float4 w0 = ((const float4*)q_w)[tx * 2];
        const float4 w1 = ((const float4*)q_w)[tx * 2 + 1];
        bf16x8 o;
        o[0] = (bf16_t)(v[0] * scq * w0.x); o[1] = (bf16_t)(v[1] * scq * w0.y);
        o[2] = (bf16_t)(v[2] * scq * w0.z); o[3] = (bf16_t)(v[3] * scq * w0.w);
        o[4] = (bf16_t)(v[4] * scq * w1.x); o[5] = (bf16_t)(v[5] * scq * w1.y);
        o[6] = (bf16_t)(v[6] * scq * w1.z); o[7] = (bf16_t)(v[7] * scq * w1.w);
        *(bf16x8*)(q_a + (long)t * QLORA + tx * 8) = o;
    }

    // ---- k side: latent 512 = 64 chunks x 8 (threads 0..63) ----
    float kv[8];
    float ssk = 0.f;
    if (tx < 64) {
        const bf16x8 a = *(const bf16x8*)(qkv + base + QLORA + tx * 8);
        if (qB) {
            const bf16x8 b = *(const bf16x8*)(qB + base + QLORA + tx * 8);
            #pragma unroll
            for (int j = 0; j < 8; j++) kv[j] = (float)a[j] + (float)b[j];
        } else {
            #pragma unroll
            for (int j = 0; j < 8; j++) kv[j] = (float)a[j];
        }
        #pragma unroll
        for (int j = 0; j < 8; j++) ssk += kv[j] * kv[j];
    }
    ssk = block_sum_256(ssk);
    const float sck = rsqrtf(ssk / (float)KVLORA + EPS_F);
    const int slot = slot_map[t];
    if (tx < 64) {
        const float4 w0 = ((const float4*)kv_w)[tx * 2];
        const float4 w1 = ((const float4*)kv_w)[tx * 2 + 1];
        float4 o0, o1;
        o0.x = kv[0] * sck * w0.x; o0.y = kv[1] * sck * w0.y;
        o0.z = kv[2] * sck * w0.z; o0.w = kv[3] * sck * w0.w;
        o1.x = kv[4] * sck * w1.x; o1.y = kv[5] * sck * w1.y;
        o1.z = kv[6] * sck * w1.z; o1.w = kv[7] * sck * w1.w;
        *(float4*)(k_out + (long)t * 576 + tx * 8)     = o0;
        *(float4*)(k_out + (long)t * 576 + tx * 8 + 4) = o1;
        *(float4*)(kc_out + (long)slot * KVLORA + tx * 8)     = o0;
        *(float4*)(kc_out + (long)slot * KVLORA + tx * 8 + 4) = o1;
    }
    if (tx < 32) {
        const int j = tx;
        const int pos = positions[t];
        const float c = cos_sin[pos * 64 + j];
        const float s = cos_sin[pos * 64 + 32 + j];
        float x1 = (float)qkv[base + QLORA + KVLORA + 2 * j];
        float x2 = (float)qkv[base + QLORA + KVLORA + 2 * j + 1];
        if (qB) {
            x1 += (float)qB[base + QLORA + KVLORA + 2 * j];
            x2 += (float)qB[base + QLORA + KVLORA + 2 * j + 1];
        }
        const float o1 = x1 * c - x2 * s;
        const float o2 = x2 * c + x1 * s;
        k_out[(long)t * 576 + 512 + j]      = o1;
        k_out[(long)t * 576 + 512 + 32 + j] = o2;
        rc_out[(long)slot * 64 + j]      = o1;
        rc_out[(long)slot * 64 + 32 + j] = o2;
    }
}

// ---- r8 skeleton + K-split wave pairs: 128x128, BK=64, 8 waves -------------
// Wave w: quadrant q=w>>1 (qr,qc), parity p=w&1 handles ks-half p only
// (addr = base + (rd_sw ^ (p<<6))): 8 ds_read + 16 MFMA per iter.
// Pairwise acc reduction through dead staging LDS; C output is bf16 (qkv
// partials are re-normalized downstream; 5x absmax headroom).
// T5: setprio(1) around the MFMA cluster (verified +10%, r14).
#define GBM 128
#define GBN 128
#define GBK 64

#define KSPLIT_TILE_COMPUTE(aa, bb)                                                          \
    bf16x8 a0, a1, a2, a3, b0, b1, b2, b3;                                                   \
    asm volatile("ds_read_b128 %0, %1 offset:0"    : "=v"(a0) : "v"(aa));                    \
    asm volatile("ds_read_b128 %0, %1 offset:2048" : "=v"(a1) : "v"(aa));                    \
    asm volatile("ds_read_b128 %0, %1 offset:4096" : "=v"(a2) : "v"(aa));                    \
    asm volatile("ds_read_b128 %0, %1 offset:6144" : "=v"(a3) : "v"(aa));                    \
    asm volatile("ds_read_b128 %0, %1 offset:0"    : "=v"(b0) : "v"(bb));                    \
    asm volatile("ds_read_b128 %0, %1 offset:2048" : "=v"(b1) : "v"(bb));                    \
    asm volatile("ds_read_b128 %0, %1 offset:4096" : "=v"(b2) : "v"(bb));                    \
    asm volatile("ds_read_b128 %0, %1 offset:6144" : "=v"(b3) : "v"(bb));                    \
    asm volatile("s_waitcnt lgkmcnt(0)" ::: "memory");                                       \
    __builtin_amdgcn_sched_barrier(0);                                                       \
    __builtin_amdgcn_s_setprio(1);                                                           \
    acc[0][0] = __builtin_amdgcn_mfma_f32_16x16x32_bf16(a0, b0, acc[0][0], 0, 0, 0);         \
    acc[0][1] = __builtin_amdgcn_mfma_f32_16x16x32_bf16(a0, b1, acc[0][1], 0, 0, 0);         \
    acc[0][2] = __builtin_amdgcn_mfma_f32_16x16x32_bf16(a0, b2, acc[0][2], 0, 0, 0);         \
    acc[0][3] = __builtin_amdgcn_mfma_f32_16x16x32_bf16(a0, b3, acc[0][3], 0, 0, 0);         \
    acc[1][0] = __builtin_amdgcn_mfma_f32_16x16x32_bf16(a1, b0, acc[1][0], 0, 0, 0);         \
    acc[1][1] = __builtin_amdgcn_mfma_f32_16x16x32_bf16(a1, b1, acc[1][1], 0, 0, 0);         \
    acc[1][2] = __builtin_amdgcn_mfma_f32_16x16x32_bf16(a1, b2, acc[1][2], 0, 0, 0);         \
    acc[1][3] = __builtin_amdgcn_mfma_f32_16x16x32_bf16(a1, b3, acc[1][3], 0, 0, 0);         \
    acc[2][0] = __builtin_amdgcn_mfma_f32_16x16x32_bf16(a2, b0, acc[2][0], 0, 0, 0);         \
    acc[2][1] = __builtin_amdgcn_mfma_f32_16x16x32_bf16(a2, b1, acc[2][1], 0, 0, 0);         \
    acc[2][2] = __builtin_amdgcn_mfma_f32_16x16x32_bf16(a2, b2, acc[2][2], 0, 0, 0);         \
    acc[2][3] = __builtin_amdgcn_mfma_f32_16x16x32_bf16(a2, b3, acc[2][3], 0, 0, 0);         \
    acc[3][0] = __builtin_amdgcn_mfma_f32_16x16x32_bf16(a3, b0, acc[3][0], 0, 0, 0);         \
    acc[3][1] = __builtin_amdgcn_mfma_f32_16x16x32_bf16(a3, b1, acc[3][1], 0, 0, 0);         \
    acc[3][2] = __builtin_amdgcn_mfma_f32_16x16x32_bf16(a3, b2, acc[3][2], 0, 0, 0);         \
    acc[3][3] = __builtin_amdgcn_mfma_f32_16x16x32_bf16(a3, b3, acc[3][3], 0, 0, 0);         \
    __builtin_amdgcn_s_setprio(0);

__global__ __launch_bounds__(512, 4) void gemm_mfma(
    const bf16_t* __restrict__ A, int lda, long sA,
    const bf16_t* __restrict__ Bt, int ldb, long sB,
    bf16_t* __restrict__ C, int ldc, long sC,
    int K, int N)
{
    __shared__ bf16_t As[2][GBM * GBK];   // 2 x 16 KB
    __shared__ bf16_t Bs[2][GBN * GBK];   // 2 x 16 KB

    const int nwg = gridDim.x * gridDim.y;
    const int bid = blockIdx.y * gridDim.x + blockIdx.x;
    const int cpx = nwg >> 3;
    const int swz = (bid & 7) * cpx + (bid >> 3);
    const int bx = swz % gridDim.x;
    const int by = swz / gridDim.x;

    const int tid = threadIdx.x;
    const int lane = tid & 63;
    const int w = tid >> 6;            // 0..7
    const int q = w >> 1;              // quadrant 0..3
    const int p = w & 1;               // ks-half parity
    const int qr = q >> 1, qc = q & 1;
    const int fr = lane & 15;
    const int kg = lane >> 4;

    const long brow = (long)by * GBM;
    const long bcol = (long)bx * GBN;

    const bf16_t* Ab = A + blockIdx.z * sA + brow * lda;
    const bf16_t* Bb = Bt + blockIdx.z * sB;
    bf16_t* Cb = C + blockIdx.z * sC + brow * ldc;

    const int srow = w * 16 + (lane >> 3);
    const int scol = (((lane & 7) ^ (lane >> 3)) * 8);

    const uint rd_sw = (uint)(((kg * 16) ^ ((fr & 7) << 4)) ^ (p << 6));
    const uint a_base = (uint)(uintptr_t)(&As[0][0]) + (uint)((qr * 64 + fr) * 128) + rd_sw;
    const uint b_base = (uint)(uintptr_t)(&Bs[0][0]) + (uint)((qc * 64 + fr) * 128) + rd_sw;

    f32x4 acc[4][4] = {};

    const int nt = K / GBK;

    auto stage = [&](int buf, int k0) {
        #pragma unroll
        for (int it = 0; it < 2; it++) {
            const int r = srow + it * 8;
            __builtin_amdgcn_global_load_lds(
                (const __attribute__((address_space(1))) void*)(Ab + (long)r * lda + k0 + scol),
                (__attribute__((address_space(3))) void*)(&As[buf][(w * 16 + it * 8) * GBK]),
                16, 0, 0);
        }
        #pragma unroll
        for (int it = 0; it < 2; it++) {
            const int r = srow + it * 8;
            long bn = bcol + r; if (bn >= N) bn = N - 1;
            __builtin_amdgcn_global_load_lds(
                (const __attribute__((address_space(1))) void*)(Bb + bn * ldb + k0 + scol),
                (__attribute__((address_space(3))) void*)(&Bs[buf][(w * 16 + it * 8) * GBK]),
                16, 0, 0);
        }
    };

    stage(0, 0);
    asm volatile("s_waitcnt vmcnt(0)" ::: "memory");
    __builtin_amdgcn_s_barrier();

    int cur = 0;
    for (int t = 0; t < nt; ++t) {
        if (t + 1 < nt) stage(cur ^ 1, (t + 1) * GBK);

        const uint aa = a_base + (uint)(cur * (GBM * GBK * 2));
        const uint bb = b_base + (uint)(cur * (GBN * GBK * 2));
        { KSPLIT_TILE_COMPUTE(aa, bb) }

        asm volatile("s_waitcnt vmcnt(0)" ::: "memory");
        __builtin_amdgcn_s_barrier();
        cur ^= 1;
    }

    float* red = (q < 2) ? (float*)&As[0][0] : (float*)&Bs[0][0];
    red += (q & 1) * 4096;   // 16 KB per quadrant
    if (p == 1) {
        #pragma unroll
        for (int i = 0; i < 4; i++)
            #pragma unroll
            for (int j = 0; j < 4; j++)
                *(f32x4*)&red[(i * 4 + j) * 256 + lane * 4] = acc[i][j];
    }
    __syncthreads();
    if (p == 0) {
        #pragma unroll
        for (int i = 0; i < 4; i++) {
            #pragma unroll
            for (int j = 0; j < 4; j++) {
                acc[i][j] += *(const f32x4*)&red[(i * 4 + j) * 256 + lane * 4];
                const int row0 = qr * 64 + i * 16 + kg * 4;
                const long col = bcol + qc * 64 + j * 16 + fr;
                if (col < N) {
                    #pragma unroll
                    for (int r = 0; r < 4; r++)
                        Cb[(long)(row0 + r) * ldc + col] = (bf16_t)acc[i][j][r];
                }
            }
        }
    }
}

// ---------------- GEMM2 (K-split pairs) with fused split_q epilogue ----------
__global__ __launch_bounds__(512, 4) void gemm2_fused(
    const bf16_t* __restrict__ A,   // q_a, lda=QLORA
    const bf16_t* __restrict__ Bt,  // wqbT, ldb=QLORA
    const float* __restrict__ cos_sin,
    const int* __restrict__ positions,
    bf16_t* __restrict__ q_nope,
    float* __restrict__ q_out)
{
    __shared__ bf16_t As[2][GBM * GBK];
    __shared__ bf16_t Bs[2][GBN * GBK];

    const int nwg = gridDim.x * gridDim.y;
    const int bid = blockIdx.y * gridDim.x + blockIdx.x;
    const int cpx = nwg >> 3;
    const int swz = (bid & 7) * cpx + (bid >> 3);
    const int bx = swz % gridDim.x;
    const int by = swz / gridDim.x;

    const int tid = threadIdx.x;
    const int lane = tid & 63;
    const int w = tid >> 6;
    const int q = w >> 1;
    const int p = w & 1;
    const int qr = q >> 1, qc = q & 1;
    const int fr = lane & 15;
    const int kg = lane >> 4;

    const int brow = by * GBM;
    const int bcol = bx * GBN;

    const bf16_t* Ab = A + (long)brow * QLORA;
    const bf16_t* Bb = Bt + (long)bcol * QLORA;

    const int srow = w * 16 + (lane >> 3);
    const int scol = (((lane & 7) ^ (lane >> 3)) * 8);

    const uint rd_sw = (uint)(((kg * 16) ^ ((fr & 7) << 4)) ^ (p << 6));
    const uint a_base = (uint)(uintptr_t)(&As[0][0]) + (uint)((qr * 64 + fr) * 128) + rd_sw;
    const uint b_base = (uint)(uintptr_t)(&Bs[0][0]) + (uint)((qc * 64 + fr) * 128) + rd_sw;

    f32x4 acc[4][4] = {};

    const int nt = QLORA / GBK;   // 24

    auto stage = [&](int buf, int k0) {
        #pragma unroll
        for (int it = 0; it < 2; it++) {
            const int r = srow + it * 8;
            __builtin_amdgcn_global_load_lds(
                (const __attribute__((address_space(1))) void*)(Ab + (long)r * QLORA + k0 + scol),
                (__attribute__((address_space(3))) void*)(&As[buf][(w * 16 + it * 8) * GBK]),
                16, 0, 0);
            __builtin_amdgcn_global_load_lds(
                (const __attribute__((address_space(1))) void*)(Bb + (long)r * QLORA + k0 + scol),
                (__attribute__((address_space(3))) void*)(&Bs[buf][(w * 16 + it * 8) * GBK]),
                16, 0, 0);
        }
    };

    stage(0, 0);
    asm volatile("s_waitcnt vmcnt(0)" ::: "memory");
    __builtin_amdgcn_s_barrier();

    int cur = 0;
    for (int t = 0; t < nt; ++t) {
        if (t + 1 < nt) stage(cur ^ 1, (t + 1) * GBK);

        const uint aa = a_base + (uint)(cur * (GBM * GBK * 2));
        const uint bb = b_base + (uint)(cur * (GBN * GBK * 2));
        { KSPLIT_TILE_COMPUTE(aa, bb) }

        asm volatile("s_waitcnt vmcnt(0)" ::: "memory");
        __builtin_amdgcn_s_barrier();
        cur ^= 1;
    }

    float* red = (q < 2) ? (float*)&As[0][0] : (float*)&Bs[0][0];
    red += (q & 1) * 4096;
    if (p == 1) {
        #pragma unroll
        for (int i = 0; i < 4; i++)
            #pragma unroll
            for (int j = 0; j < 4; j++)
                *(f32x4*)&red[(i * 4 + j) * 256 + lane * 4] = acc[i][j];
    }
    __syncthreads();
    if (p == 0) {
        #pragma unroll
        for (int i = 0; i < 4; i++) {
            #pragma unroll
            for (int j = 0; j < 4; j++) {
                acc[i][j] += *(const f32x4*)&red[(i * 4 + j) * 256 + lane * 4];
                const int row0 = qr * 64 + i * 16 + kg * 4;
                const int col  = bcol + qc * 64 + j * 16 + fr;
                const int h  = col / 192;
                const int jj = col - h * 192;
                if (jj < 128) {
                    #pragma unroll
                    for (int r = 0; r < 4; r++) {
                        const int t = brow + row0 + r;
                        q_nope[((long)h * T_TOK + t) * NOPE_D + jj] = (bf16_t)acc[i][j][r];
                    }
                } else {
                    const int idx = jj - 128;
                    const int j2 = idx >> 1;
                    const int odd = idx & 1;
                    #pragma unroll
                    for (int r = 0; r < 4; r++) {
                        const int t = brow + row0 + r;
                        const float v = acc[i][j][r];
                        const float pr = __shfl_xor(v, 1, 64);
                        const int pos = positions[t];
                        const float c = cos_sin[pos * 64 + j2];
                        const float s = cos_sin[pos * 64 + 32 + j2];
                        const float o = odd ? (v * c + pr * s) : (v * c - pr * s);
                        q_out[(long)t * 9216 + h * 576 + 512 + (odd ? 32 : 0) + j2] = o;
                    }
                }
            }
        }
    }
}

// ---------------- GEMM3: single-shot K=128 kernel ---------------------------
__global__ __launch_bounds__(512) void gemm3_k128(
    const bf16_t* __restrict__ A,   // q_nope, lda=128, head stride T*128
    const bf16_t* __restrict__ Bt,  // wkcT, ldb=2048, head stride 128
    float* __restrict__ C)          // q_out, ldc=9216, head stride 576
{
    __shared__ bf16_t As[2][GBM * GBK];
    __shared__ bf16_t Bs[2][GBN * GBK];

    const int nwg = gridDim.x * gridDim.y;
    const int bid = blockIdx.y * gridDim.x + blockIdx.x;
    const int cpx = nwg >> 3;
    const int swz = (bid & 7) * cpx + (bid >> 3);
    const int bx = swz % gridDim.x;
    const int by = swz / gridDim.x;

    const int tid = threadIdx.x;
    const int lane = tid & 63;
    const int w = tid >> 6;
    const int wr = w >> 2, wc = w & 3;   // wave tile 64x32
    const int fr = lane & 15;
    const int kg = lane >> 4;

    const long brow = (long)by * GBM;
    const long bcol = (long)bx * GBN;

    const bf16_t* Ab = A + (long)blockIdx.z * T_TOK * NOPE_D + brow * NOPE_D;
    const bf16_t* Bb = Bt + blockIdx.z * 128;
    float* Cb = C + blockIdx.z * 576 + brow * 9216;

    const int srow = w * 16 + (lane >> 3);
    const int scol = (((lane & 7) ^ (lane >> 3)) * 8);

    const uint rd_sw = (uint)((kg * 16) ^ ((fr & 7) << 4));

    #pragma unroll
    for (int kh = 0; kh < 2; kh++) {
        #pragma unroll
        for (int it = 0; it < 2; it++) {
            const int r = srow + it * 8;
            __builtin_amdgcn_global_load_lds(
                (const __attribute__((address_space(1))) void*)(Ab + (long)r * NOPE_D + kh * 64 + scol),
                (__attribute__((address_space(3))) void*)(&As[kh][(w * 16 + it * 8) * GBK]),
                16, 0, 0);
        }
        #pragma unroll
        for (int it = 0; it < 2; it++) {
            const int r = srow + it * 8;
            __builtin_amdgcn_global_load_lds(
                (const __attribute__((address_space(1))) void*)(Bb + (bcol + r) * 2048 + kh * 64 + scol),
                (__attribute__((address_space(3))) void*)(&Bs[kh][(w * 16 + it * 8) * GBK]),
                16, 0, 0);
        }
    }
    asm volatile("s_waitcnt vmcnt(0)" ::: "memory");
    __builtin_amdgcn_s_barrier();

    f32x4 acc[4][2] = {};

    #pragma unroll
    for (int kh = 0; kh < 2; kh++) {
        const uint aa  = (uint)(uintptr_t)(&As[kh][0]) + (uint)((wr * 64 + fr) * 128) + rd_sw;
        const uint bb  = (uint)(uintptr_t)(&Bs[kh][0]) + (uint)((wc * 32 + fr) * 128) + rd_sw;
        const uint aaX = aa ^ 64u;
        const uint bbX = bb ^ 64u;
        bf16x8 a00, a01, a02, a03, a10, a11, a12, a13, b00, b01, b10, b11;
        asm volatile("ds_read_b128 %0, %1 offset:0"    : "=v"(a00) : "v"(aa));
        asm volatile("ds_read_b128 %0, %1 offset:2048" : "=v"(a01) : "v"(aa));
        asm volatile("ds_read_b128 %0, %1 offset:4096" : "=v"(a02) : "v"(aa));
        asm volatile("ds_read_b128 %0, %1 offset:6144" : "=v"(a03) : "v"(aa));
        asm volatile("ds_read_b128 %0, %1 offset:0"    : "=v"(a10) : "v"(aaX));
        asm volatile("ds_read_b128 %0, %1 offset:2048" : "=v"(a11) : "v"(aaX));
        asm volatile("ds_read_b128 %0, %1 offset:4096" : "=v"(a12) : "v"(aaX));
        asm volatile("ds_read_b128 %0, %1 offset:6144" : "=v"(a13) : "v"(aaX));
        asm volatile("ds_read_b128 %0, %1 offset:0"    : "=v"(b00) : "v"(bb));
        asm volatile("ds_read_b128 %0, %1 offset:2048" : "=v"(b01) : "v"(bb));
        asm volatile("ds_read_b128 %0, %1 offset:0"    : "=v"(b10) : "v"(bbX));
        asm volatile("ds_read_b128 %0, %1 offset:2048" : "=v"(b11) : "v"(bbX));
        asm volatile("s_waitcnt lgkmcnt(0)" ::: "memory");
        __builtin_amdgcn_sched_barrier(0);

        __builtin_amdgcn_s_setprio(1);
        acc[0][0] = __builtin_amdgcn_mfma_f32_16x16x32_bf16(a00, b00, acc[0][0], 0, 0, 0);
        acc[0][1] = __builtin_amdgcn_mfma_f32_16x16x32_bf16(a00, b01, acc[0][1], 0, 0, 0);
        acc[1][0] = __builtin_amdgcn_mfma_f32_16x16x32_bf16(a01, b00, acc[1][0], 0, 0, 0);
        acc[1][1] = __builtin_amdgcn_mfma_f32_16x16x32_bf16(a01, b01, acc[1][1], 0, 0, 0);
        acc[2][0] = __builtin_amdgcn_mfma_f32_16x16x32_bf16(a02, b00, acc[2][0], 0, 0, 0);
        acc[2][1] = __builtin_amdgcn_mfma_f32_16x16x32_bf16(a02, b01, acc[2][1], 0, 0, 0);
        acc[3][0] = __builtin_amdgcn_mfma_f32_16x16x32_bf16(a03, b00, acc[3][0], 0, 0, 0);
        acc[3][1] = __builtin_amdgcn_mfma_f32_16x16x32_bf16(a03, b01, acc[3][1], 0, 0, 0);
        acc[0][0] = __builtin_amdgcn_mfma_f32_16x16x32_bf16(a10, b10, acc[0][0], 0, 0, 0);
        acc[0][1] = __builtin_amdgcn_mfma_f32_16x16x32_bf16(a10, b11, acc[0][1], 0, 0, 0);
        acc[1][0] = __builtin_amdgcn_mfma_f32_16x16x32_bf16(a11, b10, acc[1][0], 0, 0, 0);
        acc[1][1] = __builtin_amdgcn_mfma_f32_16x16x32_bf16(a11, b11, acc[1][1], 0, 0, 0);
        acc[2][0] = __builtin_amdgcn_mfma_f32_16x16x32_bf16(a12, b10, acc[2][0], 0, 0, 0);
        acc[2][1] = __builtin_amdgcn_mfma_f32_16x16x32_bf16(a12, b11, acc[2][1], 0, 0, 0);
        acc[3][0] = __builtin_amdgcn_mfma_f32_16x16x32_bf16(a13, b10, acc[3][0], 0, 0, 0);
        acc[3][1] = __builtin_amdgcn_mfma_f32_16x16x32_bf16(a13, b11, acc[3][1], 0, 0, 0);
        __builtin_amdgcn_s_setprio(0);
    }

    #pragma unroll
    for (int i = 0; i < 4; i++) {
        #pragma unroll
        for (int j = 0; j < 2; j++) {
            const int row0 = wr * 64 + i * 16 + kg * 4;
            const long col = bcol + wc * 32 + j * 16 + fr;
            #pragma unroll
            for (int r = 0; r < 4; r++)
                Cb[(long)(row0 + r) * 9216 + col] = acc[i][j][r];
        }
    }
}

// ---------------- launcher ----------------

extern "C" void kernel_launch(void* const* d_in, const int* in_sizes, int n_in,
                              void* d_out, int out_size, void* d_ws, size_t ws_size,
                              hipStream_t stream)
{
    const float* hs       = (const float*)d_in[0];
    const int*   positions= (const int*)d_in[1];
    const float* w_qkv_a  = (const float*)d_in[2];
    const float* q_a_ln_w = (const float*)d_in[3];
    const float* w_q_b    = (const float*)d_in[4];
    const float* kv_a_ln_w= (const float*)d_in[5];
    const float* w_kc     = (const float*)d_in[6];
    const float* cos_sin  = (const float*)d_in[7];
    const float* k_cache_in  = (const float*)d_in[8];
    const float* rope_cache_in = (const float*)d_in[9];
    const int*   slot_map = (const int*)d_in[10];

    float* out   = (float*)d_out;
    float* q_out = out;                       // 4096*16*576
    float* k_out = out + 37748736;            // 4096*576
    float* kc_out = out + 40108032;           // 16384*512
    float* rc_out = out + 48496640;           // 16384*64

    char* ws = (char*)d_ws;
    bf16_t* hs_bf  = (bf16_t*)(ws + 0);            // 58,720,256 B
    bf16_t* wqkvaT = (bf16_t*)(ws + 58720256);     // 30,277,632 B
    bf16_t* wqbT   = (bf16_t*)(ws + 88997888);     //  9,437,184 B
    bf16_t* wkcT   = (bf16_t*)(ws + 98435072);     //  2,097,152 B
    bf16_t* qkv0   = (bf16_t*)(ws + 100532224);    // 17,301,504 B (bf16 partial)

    const bool splitk = ws_size >= (size_t)169738240;

    bf16_t* qkv1 = nullptr;
    bf16_t* q_a;
    bf16_t* q_nope;
    if (splitk) {
        qkv1   = (bf16_t*)(ws + 117833728);        // 17,301,504 B -> ends 135,135,232
        q_a    = (bf16_t*)(ws + 0);                // hs_bf region, dead after GEMM1
        q_nope = (bf16_t*)(ws + 117833728);        // reuse qkv1 slot after rmsq_kside
    } else {
        q_a    = (bf16_t*)(ws + 135135232);
        q_nope = (bf16_t*)(ws + 100532224);        // reuse qkv0 slot
    }

    hipMemcpyAsync(kc_out, k_cache_in, (size_t)16384 * 512 * 4, hipMemcpyDeviceToDevice, stream);
    hipMemcpyAsync(rc_out, rope_cache_in, (size_t)16384 * 64 * 4, hipMemcpyDeviceToDevice, stream);

    // fused preamble: hs cast + 3 weight transposes in one launch
    preamble_kernel<<<6128, 256, 0, stream>>>(hs, w_qkv_a, w_q_b, w_kc,
                                              hs_bf, wqkvaT, wqbT, wkcT);

    // GEMM1: qkv = hs @ w_qkv_a   (4096 x 2112, K=7168), split-K=2, bf16 partials
    if (splitk) {
        gemm_mfma<<<dim3((NQKV + GBN - 1) / GBN, T_TOK / GBM, 2), 512, 0, stream>>>(
            hs_bf, H_DIM, 3584, wqkvaT, H_DIM, 3584,
            qkv0, NQKV, (long)T_TOK * NQKV, 3584, NQKV);
    } else {
        gemm_mfma<<<dim3((NQKV + GBN - 1) / GBN, T_TOK / GBM, 1), 512, 0, stream>>>(
            hs_bf, H_DIM, 0, wqkvaT, H_DIM, 0, qkv0, NQKV, 0, H_DIM, NQKV);
    }

    rmsq_kside_kernel<<<T_TOK, 256, 0, stream>>>(qkv0, qkv1, q_a_ln_w, kv_a_ln_w,
                                                 cos_sin, positions, slot_map,
                                                 q_a, k_out, kc_out, rc_out);

    // GEMM2 + fused split_q
    gemm2_fused<<<dim3(NQB / GBN, T_TOK / GBM), 512, 0, stream>>>(
        q_a, wqbT, cos_sin, positions, q_nope, q_out);

    // GEMM3 (batched over heads): single-shot K=128
    gemm3_k128<<<dim3(KVLORA / GBN, T_TOK / GBM, NHEAD), 512, 0, stream>>>(
        q_nope, wkcT, q_out);
}